// Round 1
// baseline (41218.066 us; speedup 1.0000x reference)
//
#include <hip/hip_runtime.h>
#include <hip/hip_cooperative_groups.h>

namespace cg = cooperative_groups;

// AWD-LSTM forward, T=1024 B=64 DIN=512 H=1024.
// Round 5: single persistent cooperative kernel.
//  - weights fp32->bf16 converted ONCE into 192 VGPRs/wave (B-fragments)
//  - x_t converted once per step grid-cooperatively into ws ping-pong
//  - c-state + biases in registers across all 1024 steps
//  - grid.sync() per step replaces 1024 kernel launches
// ws: hbuf[2][B*H] bf16 (256KB) + xpp[2][B*DIN] bf16 (128KB) = 384KB (< prior 520KB)

#define TT   1024
#define BB   64
#define DIN_ 512
#define HH   1024
#define BH   (BB * HH)    // 65536
#define BD   (BB * DIN_)  // 32768

typedef __attribute__((ext_vector_type(8))) short  short8;   // 8 bf16
typedef __attribute__((ext_vector_type(4))) float  floatx4;

__device__ __forceinline__ unsigned short f2bf(float f) {
    unsigned u = __builtin_bit_cast(unsigned, f);
    unsigned r = u + 0x7FFFu + ((u >> 16) & 1u);   // RNE
    return (unsigned short)(r >> 16);
}
__device__ __forceinline__ float b2f(unsigned short u) {
    return __builtin_bit_cast(float, (unsigned)u << 16);
}
// 8 consecutive fp32 -> bf16 MFMA fragment (order-preserving)
__device__ __forceinline__ short8 frag_f32(const float* __restrict__ p) {
    floatx4 f0 = *(const floatx4*)p;
    floatx4 f1 = *(const floatx4*)(p + 4);
    short8 a;
#pragma unroll
    for (int e = 0; e < 4; ++e) {
        a[e]     = (short)f2bf(f0[e]);
        a[e + 4] = (short)f2bf(f1[e]);
    }
    return a;
}
__device__ __forceinline__ float sigm(float x) { return 1.f / (1.f + __expf(-x)); }
// overflow-safe tanh: x->+inf => 1, x->-inf => -1 (no inf/inf NaN)
__device__ __forceinline__ float ftanh(float x) {
    float e = __expf(2.f * x);
    return 1.f - 2.f / (e + 1.f);
}

__global__ __launch_bounds__(256, 1) void lstm_all(
    const void* __restrict__ x,      // [T,B,DIN] fp32 (or bf16 per probe)
    const void* __restrict__ h0,
    const void* __restrict__ c0,
    const void* __restrict__ Wi,     // [4H,DIN]
    const void* __restrict__ bi,     // [4H]
    const void* __restrict__ Wh,     // [4H,H]
    const void* __restrict__ bh,     // [4H]
    const int*  __restrict__ tok,    // [T,B]
    unsigned short* __restrict__ hbuf,  // ws [2][B*H] bf16
    unsigned short* __restrict__ xpp,   // ws [2][B*DIN] bf16 (fp32-input path only)
    float* __restrict__ out)            // fp32: [T,B,H] ++ hT[B,H] ++ cT[B,H]
{
    cg::grid_group grid = cg::this_grid();
    const int tid  = threadIdx.x;
    const int wave = tid >> 6;
    const int lane = tid & 63;
    const int bid  = blockIdx.x;
    const int jb   = bid * 4;

    __shared__ float preact[64][17];
    __shared__ int   sflag;

    // ---- dtype probe (redundant per block; same verified heuristic) ----
    if (tid < 64) {
        const unsigned short* wr = (const unsigned short*)Wi;
        int pass = 0;
#pragma unroll
        for (int k = 0; k < 4; ++k) {
            unsigned e = (wr[tid * 4 + k] >> 7) & 0xFF;
            pass += (e >= 0x60 && e <= 0x7B) ? 1 : 0;
        }
        for (int off = 32; off > 0; off >>= 1) pass += __shfl_down(pass, off);
        if (tid == 0) sflag = (pass >= 200) ? 1 : 0;
    }
    __syncthreads();
    const bool isbf = (sflag != 0);

    // mfma_f32_16x16x32_bf16 lane maps (HW-verified, carried from R4):
    //   A: m = lane&15, k = (lane>>4)*8 + j     B: n = lane&15, same k
    //   D: col = lane&15, row = (lane>>4)*4 + r
    const int m    = lane & 15;
    const int colq = lane & 15;
    const int quad = lane >> 4;
    const int b_a  = wave * 16 + m;                       // batch row (A)
    const int wrow = (colq >> 2) * HH + jb + (colq & 3);  // weight row (B col n)

    // ---- one-time: weight B-fragments into registers (192 VGPRs) ----
    short8 bWh[32], bWi_[16];
    if (isbf) {
        const unsigned short* bp = (const unsigned short*)Wh + (size_t)wrow * HH + quad * 8;
#pragma unroll
        for (int ki = 0; ki < 32; ++ki) bWh[ki] = *(const short8*)(bp + ki * 32);
        const unsigned short* ip = (const unsigned short*)Wi + (size_t)wrow * DIN_ + quad * 8;
#pragma unroll
        for (int ki = 0; ki < 16; ++ki) bWi_[ki] = *(const short8*)(ip + ki * 32);
    } else {
        const float* bp = (const float*)Wh + (size_t)wrow * HH + quad * 8;
#pragma unroll
        for (int ki = 0; ki < 32; ++ki) bWh[ki] = frag_f32(bp + ki * 32);
        const float* ip = (const float*)Wi + (size_t)wrow * DIN_ + quad * 8;
#pragma unroll
        for (int ki = 0; ki < 16; ++ki) bWi_[ki] = frag_f32(ip + ki * 32);
    }

    // ---- one-time: epilogue-thread state in registers ----
    const int b  = tid >> 2;
    const int jj = tid & 3;
    const int j  = jb + jj;
    float bsum[4];
#pragma unroll
    for (int q = 0; q < 4; ++q) {
        float vbi = isbf ? b2f(((const unsigned short*)bi)[q * HH + j])
                         : ((const float*)bi)[q * HH + j];
        float vbh = isbf ? b2f(((const unsigned short*)bh)[q * HH + j])
                         : ((const float*)bh)[q * HH + j];
        bsum[q] = vbi + vbh;
    }
    float c = isbf ? b2f(((const unsigned short*)c0)[b * HH + j])
                   : ((const float*)c0)[b * HH + j];

    // ---- init: hbuf[0] slice (1 elem/thread), xpp[0] slice (16 chunks/block) ----
    {
        int idx = bid * 256 + tid;
        hbuf[idx] = isbf ? ((const unsigned short*)h0)[idx]
                         : f2bf(((const float*)h0)[idx]);
    }
    if (!isbf && tid < 16) {
        const float* xs = (const float*)x + (size_t)(bid * 16 + tid) * 8;
        *(short8*)(xpp + (size_t)(bid * 16 + tid) * 8) = frag_f32(xs);
    }
    grid.sync();

    const unsigned short* xg = (const unsigned short*)x;

    for (int t = 0; t < TT; ++t) {
        // ---- h @ Wh^T, K=1024; 4-way split accumulator chain ----
        const unsigned short* hsrc = hbuf + (size_t)(t & 1) * BH + b_a * HH + quad * 8;
        floatx4 a0 = {0.f,0.f,0.f,0.f}, a1 = {0.f,0.f,0.f,0.f};
        floatx4 a2 = {0.f,0.f,0.f,0.f}, a3 = {0.f,0.f,0.f,0.f};
#pragma unroll
        for (int ki = 0; ki < 32; ki += 4) {
            a0 = __builtin_amdgcn_mfma_f32_16x16x32_bf16(*(const short8*)(hsrc + (ki+0)*32), bWh[ki+0], a0, 0,0,0);
            a1 = __builtin_amdgcn_mfma_f32_16x16x32_bf16(*(const short8*)(hsrc + (ki+1)*32), bWh[ki+1], a1, 0,0,0);
            a2 = __builtin_amdgcn_mfma_f32_16x16x32_bf16(*(const short8*)(hsrc + (ki+2)*32), bWh[ki+2], a2, 0,0,0);
            a3 = __builtin_amdgcn_mfma_f32_16x16x32_bf16(*(const short8*)(hsrc + (ki+3)*32), bWh[ki+3], a3, 0,0,0);
        }
        floatx4 hacc = (a0 + a1) + (a2 + a3);

        // reset at consumption: zero h-part rows where t>1 && tok[t-1]==0
        if (t > 1) {
#pragma unroll
            for (int r = 0; r < 4; ++r) {
                int bb_ = wave * 16 + quad * 4 + r;
                if (tok[(t - 1) * BB + bb_] == 0) hacc[r] = 0.f;
            }
        }

        // ---- x_t @ Wi^T, K=512 (bf16 source: direct or ws ping-pong) ----
        const unsigned short* xsrc = (isbf ? xg + (size_t)t * BD
                                           : xpp + (size_t)(t & 1) * BD)
                                     + b_a * DIN_ + quad * 8;
        floatx4 x0 = {0.f,0.f,0.f,0.f}, x1 = {0.f,0.f,0.f,0.f};
#pragma unroll
        for (int ki = 0; ki < 16; ki += 2) {
            x0 = __builtin_amdgcn_mfma_f32_16x16x32_bf16(*(const short8*)(xsrc + (ki+0)*32), bWi_[ki+0], x0, 0,0,0);
            x1 = __builtin_amdgcn_mfma_f32_16x16x32_bf16(*(const short8*)(xsrc + (ki+1)*32), bWi_[ki+1], x1, 0,0,0);
        }
        floatx4 p4 = (hacc + x0) + x1;

#pragma unroll
        for (int r = 0; r < 4; ++r)
            preact[wave * 16 + quad * 4 + r][colq] = p4[r];

        // cooperative convert of x_{t+1} (fp32 path): latency hides under epilogue
        if (!isbf && t < TT - 1 && tid < 16) {
            const float* xs = (const float*)x + (size_t)(t + 1) * BD + (size_t)(bid * 16 + tid) * 8;
            *(short8*)(xpp + (size_t)((t + 1) & 1) * BD + (size_t)(bid * 16 + tid) * 8) = frag_f32(xs);
        }
        __syncthreads();

        // ---- cell epilogue: thread -> (b = tid>>2, jj = tid&3) ----
        float ig = sigm(preact[b][0 * 4 + jj] + bsum[0]);
        float fg = sigm(preact[b][1 * 4 + jj] + bsum[1]);
        float og = sigm(preact[b][2 * 4 + jj] + bsum[2]);
        float gg = ftanh(preact[b][3 * 4 + jj] + bsum[3]);   // g from LAST quarter (source quirk)

        float keep = (t > 1 && tok[(t - 1) * BB + b] == 0) ? 0.f : 1.f;
        c = fg * (c * keep) + ig * gg;
        float h = og * ftanh(c);

        out[(size_t)t * BH + b * HH + j] = h;                       // fp32 output
        hbuf[(size_t)((t + 1) & 1) * BH + b * HH + j] = f2bf(h);    // pre-reset h state
        if (t == TT - 1) {
            out[(size_t)TT * BH + b * HH + j]      = h;   // hT
            out[(size_t)TT * BH + BH + b * HH + j] = c;   // cT
        }
        grid.sync();   // h_{t+1} visible grid-wide; also fences preact reuse
    }
}

extern "C" void kernel_launch(void* const* d_in, const int* in_sizes, int n_in,
                              void* d_out, int out_size, void* d_ws, size_t ws_size,
                              hipStream_t stream) {
    void* x  = d_in[0];
    void* h0 = d_in[1];
    void* c0 = d_in[2];
    void* Wi = d_in[3];
    void* bi = d_in[4];
    void* Wh = d_in[5];
    void* bh = d_in[6];
    void* tk = d_in[7];
    void* out = d_out;

    void* hbuf = d_ws;                                              // 262144 B
    void* xpp  = (void*)((char*)d_ws + 2 * BH * sizeof(unsigned short)); // +131072 B

    void* args[] = { &x, &h0, &c0, &Wi, &bi, &Wh, &bh, &tk, &hbuf, &xpp, &out };
    hipLaunchCooperativeKernel((void*)lstm_all, dim3(256), dim3(256), args, 0, stream);
}

// Round 2
// 15382.750 us; speedup vs baseline: 2.6795x; 2.6795x over previous
//
#include <hip/hip_runtime.h>

// AWD-LSTM forward, T=1024 B=64 DIN=512 H=1024.
// Round 6: back to 1024-launch structure (graph-replayed; launch = the sync).
//  - NEW: one-time prep stages Wh/Wi (and all of x, ws permitting) into ws as
//    bf16, so the step kernel is a branch-free all-bf16 MFMA loop:
//    half the L2 bytes, zero per-step convert VALU.
//  - bias sum (bi+bh) precomputed fp32 in ws.
//  - MODE 0: x+weights staged (needs ~76.5MB ws)
//    MODE 1: weights staged, x ping-pong converted in-step (needs ~12.7MB ws)
//    MODE 2: legacy R4 path (verified), needs ~0.6MB ws
// Numerics identical to R4/R5 (same RNE bf16 conversions, fp32 epilogue).

#define TT   1024
#define BB   64
#define DIN_ 512
#define HH   1024
#define BH   (BB * HH)    // 65536
#define BD   (BB * DIN_)  // 32768

typedef __attribute__((ext_vector_type(8))) short  short8;   // 8 bf16
typedef __attribute__((ext_vector_type(4))) float  floatx4;

__device__ __forceinline__ unsigned short f2bf(float f) {
    unsigned u = __builtin_bit_cast(unsigned, f);
    unsigned r = u + 0x7FFFu + ((u >> 16) & 1u);   // RNE
    return (unsigned short)(r >> 16);
}
__device__ __forceinline__ float b2f(unsigned short u) {
    return __builtin_bit_cast(float, (unsigned)u << 16);
}
// 8 consecutive fp32 -> bf16 fragment (order-preserving)
__device__ __forceinline__ short8 frag_f32(const float* __restrict__ p) {
    floatx4 f0 = *(const floatx4*)p;
    floatx4 f1 = *(const floatx4*)(p + 4);
    short8 a;
#pragma unroll
    for (int e = 0; e < 4; ++e) {
        a[e]     = (short)f2bf(f0[e]);
        a[e + 4] = (short)f2bf(f1[e]);
    }
    return a;
}
__device__ __forceinline__ float sigm(float x) { return 1.f / (1.f + __expf(-x)); }
// overflow-safe tanh (verified R5): x->±inf => ±1, no NaN
__device__ __forceinline__ float ftanh(float x) {
    float e = __expf(2.f * x);
    return 1.f - 2.f / (e + 1.f);
}

// ---- ws layout (bytes) ----
#define WS_FLAG  0                    // int
#define WS_BSUM  1024                 // float[4096]        (16 KB)
#define WS_CWS   17408                // float[65536]       (256 KB)
#define WS_HBUF  279552               // ushort[2][65536]   (256 KB)
#define WS_WHB   541696               // ushort[4H*H]       (8 MB)
#define WS_WIB   8930304              // ushort[4H*DIN]     (4 MB)
#define WS_XTOP  13124608             // MODE0: ushort[T*BD] (64 MB) / MODE1: ushort[2*BD] (128 KB)
#define NEED_COMPACT (13124608ull + 2ull * BD * 2ull)       // ~12.7 MB
#define NEED_FULL    (13124608ull + (size_t)TT * BD * 2ull) // ~76.5 MB

// Probe first 256 ushorts of Wi (uniform(+-2^-5)): bf16 -> ~100% exponent in
// [0x60,0x7B]; fp32-as-ushort -> ~55%.
__global__ __launch_bounds__(64) void dtype_probe(const unsigned short* __restrict__ wi_raw,
                                                  int* __restrict__ flag) {
    int lane = threadIdx.x;
    int pass = 0;
#pragma unroll
    for (int k = 0; k < 4; ++k) {
        unsigned e = (wi_raw[lane * 4 + k] >> 7) & 0xFF;
        pass += (e >= 0x60 && e <= 0x7B) ? 1 : 0;
    }
    for (int off = 32; off > 0; off >>= 1) pass += __shfl_down(pass, off);
    if (lane == 0) *flag = (pass >= 200) ? 1 : 0;
}

// init: h0 -> hbuf[0] bf16, c0 -> c_ws fp32, bi+bh -> bsum fp32,
//       (mode1) x_0 -> xpp[0] bf16
__global__ __launch_bounds__(256) void lstm_init(
    const void* __restrict__ h0, const void* __restrict__ c0,
    const void* __restrict__ bi, const void* __restrict__ bh,
    const void* __restrict__ x,
    const int* __restrict__ flag,
    unsigned short* __restrict__ hbuf0, float* __restrict__ c_ws,
    float* __restrict__ bsum, unsigned short* __restrict__ xpp,
    int stage_x0)
{
    const bool isbf = (*flag != 0);
    int i = blockIdx.x * 256 + threadIdx.x;    // 65536 threads
    hbuf0[i] = isbf ? ((const unsigned short*)h0)[i] : f2bf(((const float*)h0)[i]);
    c_ws[i]  = isbf ? b2f(((const unsigned short*)c0)[i]) : ((const float*)c0)[i];
    if (i < 4 * HH) {
        float vbi = isbf ? b2f(((const unsigned short*)bi)[i]) : ((const float*)bi)[i];
        float vbh = isbf ? b2f(((const unsigned short*)bh)[i]) : ((const float*)bh)[i];
        bsum[i] = vbi + vbh;
    }
    if (stage_x0 && i < BD / 8) {
        if (isbf) *(short8*)(xpp + (size_t)i * 8) =
                      *(const short8*)((const unsigned short*)x + (size_t)i * 8);
        else      *(short8*)(xpp + (size_t)i * 8) = frag_f32((const float*)x + (size_t)i * 8);
    }
}

// one-time staging: Wh, Wi (and optionally all of x) -> bf16 in ws
__global__ __launch_bounds__(256) void conv_ws(
    const void* __restrict__ Wh, const void* __restrict__ Wi,
    const void* __restrict__ x, const int* __restrict__ flag,
    unsigned short* __restrict__ whb, unsigned short* __restrict__ wib,
    unsigned short* __restrict__ xbf, int do_x)
{
    const bool isbf = (*flag != 0);
    const size_t NWH = (size_t)4 * HH * HH / 8;      // 524288 chunks
    const size_t NWI = (size_t)4 * HH * DIN_ / 8;    // 262144
    const size_t NX  = do_x ? (size_t)TT * BD / 8 : 0;  // 4194304
    const size_t total = NWH + NWI + NX;
    for (size_t i = (size_t)blockIdx.x * 256 + threadIdx.x; i < total;
         i += (size_t)gridDim.x * 256) {
        const void* src; unsigned short* dst; size_t off;
        if (i < NWH)            { src = Wh; dst = whb; off = i; }
        else if (i < NWH + NWI) { src = Wi; dst = wib; off = i - NWH; }
        else                    { src = x;  dst = xbf; off = i - NWH - NWI; }
        if (isbf) *(short8*)(dst + off * 8) =
                      *(const short8*)((const unsigned short*)src + off * 8);
        else      *(short8*)(dst + off * 8) = frag_f32((const float*)src + off * 8);
    }
}

// One timestep. Block covers jb = blockIdx.x*4 (4 h-cols x 4 gates = 16 cols).
// preact[64x16] = keep*(h @ Wh^T) + x_t @ Wi^T  via mfma_f32_16x16x32_bf16.
// MODE 0: A/B all bf16 from ws (x pre-staged for all t)
// MODE 1: like 0 but x from ping-pong; stages x_{t+1} in-step
// MODE 2: legacy R4 (weights/x converted per step per dtype flag)
template<int MODE>
__global__ __launch_bounds__(256) void lstm_step(
    const unsigned short* __restrict__ xb,    // MODE0: xbf[T*BD]; MODE1: xpp[2*BD]
    unsigned short* __restrict__ xpp_w,       // MODE1: writable xpp
    const unsigned short* __restrict__ whb,   // [4H*H] bf16
    const unsigned short* __restrict__ wib,   // [4H*DIN] bf16
    const float* __restrict__ bsum,           // [4H] fp32 (bi+bh)
    const int*  __restrict__ tok,             // [T,B]
    unsigned short* __restrict__ hbuf,        // [2][B*H] bf16
    float* __restrict__ c_ws,                 // [B*H] fp32
    float* __restrict__ out,                  // fp32: [T,B,H] ++ hT ++ cT
    const void* __restrict__ xraw,            // raw x (MODE1 staging / MODE2)
    const void* __restrict__ WiRaw,
    const void* __restrict__ WhRaw,
    const int*  __restrict__ flag,
    int t)
{
    const int tid  = threadIdx.x;
    const int wave = tid >> 6;
    const int lane = tid & 63;
    const int jb   = blockIdx.x * 4;

    __shared__ float preact[64][17];

    // mfma_f32_16x16x32_bf16 lane maps (HW-verified, carried from R4):
    //   A: m = lane&15, k = (lane>>4)*8 + j     B: n = lane&15, same k
    //   D: col = lane&15, row = (lane>>4)*4 + r
    const int m    = lane & 15;
    const int colq = lane & 15;
    const int quad = lane >> 4;
    const int b_a  = wave * 16 + m;                       // batch row (A)
    const int wrow = (colq >> 2) * HH + jb + (colq & 3);  // weight row (B col n)

    floatx4 a0 = {0.f,0.f,0.f,0.f}, a1 = {0.f,0.f,0.f,0.f};
    floatx4 a2 = {0.f,0.f,0.f,0.f}, a3 = {0.f,0.f,0.f,0.f};
    const unsigned short* hsrc = hbuf + (size_t)(t & 1) * BH + b_a * HH + quad * 8;

    // ---- h @ Wh^T, K=1024 ----
    if constexpr (MODE < 2) {
        const unsigned short* bp = whb + (size_t)wrow * HH + quad * 8;
#pragma unroll
        for (int ki = 0; ki < 32; ki += 4) {
            a0 = __builtin_amdgcn_mfma_f32_16x16x32_bf16(*(const short8*)(hsrc + (ki+0)*32), *(const short8*)(bp + (ki+0)*32), a0, 0,0,0);
            a1 = __builtin_amdgcn_mfma_f32_16x16x32_bf16(*(const short8*)(hsrc + (ki+1)*32), *(const short8*)(bp + (ki+1)*32), a1, 0,0,0);
            a2 = __builtin_amdgcn_mfma_f32_16x16x32_bf16(*(const short8*)(hsrc + (ki+2)*32), *(const short8*)(bp + (ki+2)*32), a2, 0,0,0);
            a3 = __builtin_amdgcn_mfma_f32_16x16x32_bf16(*(const short8*)(hsrc + (ki+3)*32), *(const short8*)(bp + (ki+3)*32), a3, 0,0,0);
        }
    } else {
        const bool isbf = (*flag != 0);
        if (isbf) {
            const unsigned short* bp = (const unsigned short*)WhRaw + (size_t)wrow * HH + quad * 8;
#pragma unroll
            for (int ki = 0; ki < 32; ki += 2) {
                a0 = __builtin_amdgcn_mfma_f32_16x16x32_bf16(*(const short8*)(hsrc + (ki+0)*32), *(const short8*)(bp + (ki+0)*32), a0, 0,0,0);
                a1 = __builtin_amdgcn_mfma_f32_16x16x32_bf16(*(const short8*)(hsrc + (ki+1)*32), *(const short8*)(bp + (ki+1)*32), a1, 0,0,0);
            }
        } else {
            const float* bp = (const float*)WhRaw + (size_t)wrow * HH + quad * 8;
#pragma unroll
            for (int ki = 0; ki < 32; ki += 2) {
                a0 = __builtin_amdgcn_mfma_f32_16x16x32_bf16(*(const short8*)(hsrc + (ki+0)*32), frag_f32(bp + (ki+0)*32), a0, 0,0,0);
                a1 = __builtin_amdgcn_mfma_f32_16x16x32_bf16(*(const short8*)(hsrc + (ki+1)*32), frag_f32(bp + (ki+1)*32), a1, 0,0,0);
            }
        }
    }
    floatx4 hacc = (a0 + a1) + (a2 + a3);

    // reset at consumption: zero h-part rows where t>1 && tok[t-1]==0
    if (t > 1) {
#pragma unroll
        for (int r = 0; r < 4; ++r) {
            int bb_ = wave * 16 + quad * 4 + r;
            if (tok[(t - 1) * BB + bb_] == 0) hacc[r] = 0.f;
        }
    }

    // ---- x_t @ Wi^T, K=512 ----
    floatx4 x0 = {0.f,0.f,0.f,0.f}, x1 = {0.f,0.f,0.f,0.f};
    if constexpr (MODE < 2) {
        const unsigned short* xsrc =
            (MODE == 0 ? xb + (size_t)t * BD : xb + (size_t)(t & 1) * BD)
            + b_a * DIN_ + quad * 8;
        const unsigned short* ip = wib + (size_t)wrow * DIN_ + quad * 8;
#pragma unroll
        for (int ki = 0; ki < 16; ki += 2) {
            x0 = __builtin_amdgcn_mfma_f32_16x16x32_bf16(*(const short8*)(xsrc + (ki+0)*32), *(const short8*)(ip + (ki+0)*32), x0, 0,0,0);
            x1 = __builtin_amdgcn_mfma_f32_16x16x32_bf16(*(const short8*)(xsrc + (ki+1)*32), *(const short8*)(ip + (ki+1)*32), x1, 0,0,0);
        }
    } else {
        const bool isbf = (*flag != 0);
        if (isbf) {
            const unsigned short* ap = (const unsigned short*)xraw + (size_t)t * BD + b_a * DIN_ + quad * 8;
            const unsigned short* bp = (const unsigned short*)WiRaw + (size_t)wrow * DIN_ + quad * 8;
#pragma unroll
            for (int ki = 0; ki < 16; ki += 2) {
                x0 = __builtin_amdgcn_mfma_f32_16x16x32_bf16(*(const short8*)(ap + (ki+0)*32), *(const short8*)(bp + (ki+0)*32), x0, 0,0,0);
                x1 = __builtin_amdgcn_mfma_f32_16x16x32_bf16(*(const short8*)(ap + (ki+1)*32), *(const short8*)(bp + (ki+1)*32), x1, 0,0,0);
            }
        } else {
            const float* ap = (const float*)xraw + (size_t)t * BD + b_a * DIN_ + quad * 8;
            const float* bp = (const float*)WiRaw + (size_t)wrow * DIN_ + quad * 8;
#pragma unroll
            for (int ki = 0; ki < 16; ki += 2) {
                x0 = __builtin_amdgcn_mfma_f32_16x16x32_bf16(frag_f32(ap + (ki+0)*32), frag_f32(bp + (ki+0)*32), x0, 0,0,0);
                x1 = __builtin_amdgcn_mfma_f32_16x16x32_bf16(frag_f32(ap + (ki+1)*32), frag_f32(bp + (ki+1)*32), x1, 0,0,0);
            }
        }
    }
    floatx4 p4 = (hacc + x0) + x1;

#pragma unroll
    for (int r = 0; r < 4; ++r)
        preact[wave * 16 + quad * 4 + r][colq] = p4[r];

    // MODE1: stage x_{t+1} into the other ping-pong half (hides under epilogue)
    if constexpr (MODE == 1) {
        if (t < TT - 1 && tid < 16) {
            const bool isbf = (*flag != 0);
            size_t ch = (size_t)blockIdx.x * 16 + tid;     // 4096 chunks == BD/8
            unsigned short* dst = xpp_w + (size_t)((t + 1) & 1) * BD + ch * 8;
            if (isbf) *(short8*)dst =
                *(const short8*)((const unsigned short*)xraw + (size_t)(t + 1) * BD + ch * 8);
            else *(short8*)dst = frag_f32((const float*)xraw + (size_t)(t + 1) * BD + ch * 8);
        }
    }
    __syncthreads();

    // ---- cell epilogue: thread -> (b = tid>>2, jj = tid&3) ----
    const int b  = tid >> 2;
    const int jj = tid & 3;
    const int j  = jb + jj;

    float ig = sigm(preact[b][0 * 4 + jj] + bsum[0 * HH + j]);
    float fg = sigm(preact[b][1 * 4 + jj] + bsum[1 * HH + j]);
    float og = sigm(preact[b][2 * 4 + jj] + bsum[2 * HH + j]);
    float gg = ftanh(preact[b][3 * 4 + jj] + bsum[3 * HH + j]);  // g from LAST quarter

    float keep   = (t > 1 && tok[(t - 1) * BB + b] == 0) ? 0.f : 1.f;
    float c_prev = c_ws[b * HH + j] * keep;
    float c_t    = fg * c_prev + ig * gg;
    float h_t    = og * ftanh(c_t);

    out[(size_t)t * BH + b * HH + j] = h_t;             // fp32 output
    c_ws[b * HH + j] = c_t;                             // raw c (keep at read)
    hbuf[(size_t)((t + 1) & 1) * BH + b * HH + j] = f2bf(h_t);  // pre-reset h

    if (t == TT - 1) {
        out[(size_t)TT * BH + b * HH + j]      = h_t;   // hT
        out[(size_t)TT * BH + BH + b * HH + j] = c_t;   // cT
    }
}

extern "C" void kernel_launch(void* const* d_in, const int* in_sizes, int n_in,
                              void* d_out, int out_size, void* d_ws, size_t ws_size,
                              hipStream_t stream) {
    const void* x  = d_in[0];
    const void* h0 = d_in[1];
    const void* c0 = d_in[2];
    const void* Wi = d_in[3];
    const void* bi = d_in[4];
    const void* Wh = d_in[5];
    const void* bh = d_in[6];
    const int* tok = (const int*)d_in[7];
    float* out = (float*)d_out;

    char* ws = (char*)d_ws;
    int*            flag = (int*)(ws + WS_FLAG);
    float*          bsum = (float*)(ws + WS_BSUM);
    float*          c_ws = (float*)(ws + WS_CWS);
    unsigned short* hbuf = (unsigned short*)(ws + WS_HBUF);
    unsigned short* whb  = (unsigned short*)(ws + WS_WHB);
    unsigned short* wib  = (unsigned short*)(ws + WS_WIB);
    unsigned short* xtop = (unsigned short*)(ws + WS_XTOP);

    const int mode = (ws_size >= NEED_FULL) ? 0 : (ws_size >= NEED_COMPACT) ? 1 : 2;

    dtype_probe<<<1, 64, 0, stream>>>((const unsigned short*)Wi, flag);
    lstm_init<<<256, 256, 0, stream>>>(h0, c0, bi, bh, x, flag, hbuf, c_ws,
                                       bsum, xtop, (mode == 1) ? 1 : 0);
    if (mode < 2)
        conv_ws<<<2048, 256, 0, stream>>>(Wh, Wi, x, flag, whb, wib, xtop,
                                          (mode == 0) ? 1 : 0);

    for (int t = 0; t < TT; ++t) {
        if (mode == 0)
            lstm_step<0><<<256, 256, 0, stream>>>(xtop, xtop, whb, wib, bsum, tok,
                                                  hbuf, c_ws, out, x, Wi, Wh, flag, t);
        else if (mode == 1)
            lstm_step<1><<<256, 256, 0, stream>>>(xtop, xtop, whb, wib, bsum, tok,
                                                  hbuf, c_ws, out, x, Wi, Wh, flag, t);
        else
            lstm_step<2><<<256, 256, 0, stream>>>(nullptr, nullptr, nullptr, nullptr,
                                                  bsum, tok, hbuf, c_ws, out,
                                                  x, Wi, Wh, flag, t);
    }
}